// Round 1
// baseline (967.206 us; speedup 1.0000x reference)
//
#include <hip/hip_runtime.h>

#define NB 64
#define TSTEPS 1024
#define EE 256
#define HH 128
#define MM (NB * TSTEPS)   // 65536 rows
#define GXC 768            // 384 fwd gates + 384 bwd gates
#define BOT 32

typedef float    f32x4 __attribute__((ext_vector_type(4)));
typedef _Float16 f16x2 __attribute__((ext_vector_type(2)));
typedef _Float16 f16x4 __attribute__((ext_vector_type(4)));
typedef _Float16 f16x8 __attribute__((ext_vector_type(8)));

#if defined(__has_builtin)
#if __has_builtin(__builtin_amdgcn_fdot2)
#define HAVE_FDOT2 1
#endif
#endif

__device__ __forceinline__ float fdot2f(f16x2 a, f16x2 b, float c) {
#ifdef HAVE_FDOT2
  return __builtin_amdgcn_fdot2(a, b, c, false);
#else
  return c + (float)a[0] * (float)b[0] + (float)a[1] * (float)b[1];
#endif
}

__device__ __forceinline__ f16x2 mkh2(float a, float b) {
  f16x2 r; r[0] = (_Float16)a; r[1] = (_Float16)b; return r;
}

// ---------------------------------------------------------------------------
// Kernel A: gx[m][g] = sum_e x[m][e] * w_ih[g][e]   (f16 MFMA, f32 accum)
// cols 0..383 = fwd gates, 384..767 = bwd gates. Biases added in kernel B.
// 128x128 tile per block, K chunked by 64. LDS stride 72 halfs (pad 8):
// frag b128 reads land 2-way max (free per m136).
// ---------------------------------------------------------------------------
__global__ __launch_bounds__(256) void gx_gemm(
    const float* __restrict__ x, const float* __restrict__ wf,
    const float* __restrict__ wb, _Float16* __restrict__ gx) {
  __shared__ _Float16 As[128 * 72];
  __shared__ _Float16 Bs[128 * 72];
  const int tid = threadIdx.x;
  const int m0  = blockIdx.x * 128;
  const int by  = blockIdx.y;  // 0..5 (3 col-blocks per direction)
  const float* wsrc = (by < 3) ? (wf + (size_t)(by * 128) * 256)
                               : (wb + (size_t)((by - 3) * 128) * 256);
  const int g0 = by * 128;

  const int lane = tid & 63;
  const int wid  = tid >> 6;
  const int wr = wid & 1, wc = wid >> 1;  // 2x2 wave grid, 64x64 per wave
  const int fm = lane & 15;               // fragment m/n index
  const int fk = (lane >> 4) * 8;         // fragment k offset (8 contiguous)

  f32x4 acc[4][4];
#pragma unroll
  for (int a = 0; a < 4; ++a)
#pragma unroll
    for (int b = 0; b < 4; ++b) acc[a][b] = (f32x4)0.0f;

  for (int kc = 0; kc < 4; ++kc) {
    const int k0 = kc * 64;
    if (kc) __syncthreads();
#pragma unroll
    for (int i = 0; i < 8; ++i) {
      int idx = tid + i * 256;          // float4 index within 128x64 chunk
      int row = idx >> 4;
      int k4  = (idx & 15) * 4;
      float4 av = *(const float4*)(x + (size_t)(m0 + row) * 256 + k0 + k4);
      float4 bv = *(const float4*)(wsrc + (size_t)row * 256 + k0 + k4);
      f16x4 ah, bh;
      ah[0] = (_Float16)av.x; ah[1] = (_Float16)av.y;
      ah[2] = (_Float16)av.z; ah[3] = (_Float16)av.w;
      bh[0] = (_Float16)bv.x; bh[1] = (_Float16)bv.y;
      bh[2] = (_Float16)bv.z; bh[3] = (_Float16)bv.w;
      *(f16x4*)&As[row * 72 + k4] = ah;
      *(f16x4*)&Bs[row * 72 + k4] = bh;
    }
    __syncthreads();
#pragma unroll
    for (int ks = 0; ks < 2; ++ks) {
      f16x8 af[4], bf[4];
#pragma unroll
      for (int tmn = 0; tmn < 4; ++tmn) {
        af[tmn] = *(const f16x8*)&As[(wr * 64 + tmn * 16 + fm) * 72 + ks * 32 + fk];
        bf[tmn] = *(const f16x8*)&Bs[(wc * 64 + tmn * 16 + fm) * 72 + ks * 32 + fk];
      }
#pragma unroll
      for (int tm = 0; tm < 4; ++tm)
#pragma unroll
        for (int tn = 0; tn < 4; ++tn)
          acc[tm][tn] = __builtin_amdgcn_mfma_f32_16x16x32_f16(
              af[tm], bf[tn], acc[tm][tn], 0, 0, 0);
    }
  }

  // epilogue: C/D layout col = lane&15, row = (lane>>4)*4 + reg  [m89/m91]
  const int rq = (lane >> 4) * 4;
#pragma unroll
  for (int tm = 0; tm < 4; ++tm)
#pragma unroll
    for (int tn = 0; tn < 4; ++tn)
#pragma unroll
      for (int v = 0; v < 4; ++v) {
        int m = m0 + wr * 64 + tm * 16 + rq + v;
        int g = g0 + wc * 64 + tn * 16 + fm;
        gx[(size_t)m * GXC + g] = (_Float16)acc[tm][tn][v];
      }
}

// ---------------------------------------------------------------------------
// Kernel B: GRU scan. 128 blocks = 64 batch x 2 dirs, 256 thr = 128 h x 2 K-halves.
// w_hh rows (r,z,n for one h index, one K-half) live in VGPRs as f16x2;
// h lives in LDS (f16, broadcast reads); v_dot2_f32_f16 inner product.
// ---------------------------------------------------------------------------
__global__ __launch_bounds__(256) void gru_scan(
    const _Float16* __restrict__ gx,
    const float* __restrict__ whf, const float* __restrict__ whb,
    const float* __restrict__ bihf, const float* __restrict__ bhhf,
    const float* __restrict__ bihb, const float* __restrict__ bhhb,
    _Float16* __restrict__ pros) {
  const int bid = blockIdx.x;
  const int dir = bid & 1;
  const int n   = bid >> 1;
  const float* whh = dir ? whb : whf;
  const float* bih = dir ? bihb : bihf;
  const float* bhh = dir ? bhhb : bhhf;

  const int tid = threadIdx.x;
  const int j = tid & 127;   // h index
  const int c = tid >> 7;    // K-half (wave-uniform)

  __shared__ __align__(16) _Float16 hsh[128];
  __shared__ float pr[128], pz[128], pn[128];

  // preload w_hh rows j (r), 128+j (z), 256+j (n), k in [c*64, c*64+64)
  f16x2 wrk[32], wzk[32], wnk[32];
  {
    const int kb = c * 64;
#pragma unroll
    for (int i = 0; i < 32; ++i) {
      int k = kb + 2 * i;
      float2 a = *(const float2*)(whh + (size_t)j * HH + k);
      float2 b = *(const float2*)(whh + (size_t)(HH + j) * HH + k);
      float2 d = *(const float2*)(whh + (size_t)(2 * HH + j) * HH + k);
      wrk[i] = mkh2(a.x, a.y);
      wzk[i] = mkh2(b.x, b.y);
      wnk[i] = mkh2(d.x, d.y);
    }
  }
  float br = 0.f, bz = 0.f, bni = 0.f, bnh = 0.f;
  if (!c) {
    br  = bih[j] + bhh[j];                    // r: both biases merge
    bz  = bih[HH + j] + bhh[HH + j];          // z: both biases merge
    bni = bih[2 * HH + j];                    // n: b_ih outside reset gate
    bnh = bhh[2 * HH + j];                    // n: b_hh inside reset gate
  }
  if (tid < 128) hsh[tid] = (_Float16)0.f;
  __syncthreads();

  for (int t = 0; t < TSTEPS; ++t) {
    const int tt = dir ? (TSTEPS - 1 - t) : t;
    const _Float16* gxrow = gx + ((size_t)(n * TSTEPS + tt)) * GXC + dir * 384;
    float gxr = 0.f, gxz = 0.f, gxn = 0.f;
    if (!c) {  // prefetch: independent of h, latency hides under dot phase
      gxr = (float)gxrow[j];
      gxz = (float)gxrow[HH + j];
      gxn = (float)gxrow[2 * HH + j];
    }
    float ar = 0.f, az = 0.f, an = 0.f;
    const f16x8* hp = (const f16x8*)&hsh[c * 64];
#pragma unroll
    for (int i = 0; i < 8; ++i) {
      f16x8 hv = hp[i];
#pragma unroll
      for (int q = 0; q < 4; ++q) {
        f16x2 hh; hh[0] = hv[2 * q]; hh[1] = hv[2 * q + 1];
        int idx = i * 4 + q;
        ar = fdot2f(wrk[idx], hh, ar);
        az = fdot2f(wzk[idx], hh, az);
        an = fdot2f(wnk[idx], hh, an);
      }
    }
    if (c) { pr[j] = ar; pz[j] = az; pn[j] = an; }
    __syncthreads();
    if (!c) {
      float ghr = ar + pr[j], ghz = az + pz[j], ghn = an + pn[j];
      float rv = 1.f / (1.f + __expf(-(gxr + br + ghr)));
      float zv = 1.f / (1.f + __expf(-(gxz + bz + ghz)));
      float na = gxn + bni + rv * (ghn + bnh);
      na = fminf(15.f, fmaxf(-15.f, na));
      float e  = __expf(-2.f * na);
      float nn = (1.f - e) / (1.f + e);
      float hold = (float)hsh[j];
      float hnew = nn + zv * (hold - nn);    // (1-z)*n + z*h
      hsh[j] = (_Float16)hnew;
      pros[((size_t)(n * TSTEPS + tt)) * EE + dir * HH + j] = (_Float16)hnew;
    }
    __syncthreads();
  }
}

// ---------------------------------------------------------------------------
// Kernel C: out[m][o] = pros[m][:] . w_out[o][:] + b_out[o]
// 256 rows x 32 cols per block; thread = 8 rows x 4 cols (cols strided by 8
// so ds_read_b128 at LDS stride 260 covers all 32 banks conflict-free).
// ---------------------------------------------------------------------------
__global__ __launch_bounds__(256) void out_proj(
    const _Float16* __restrict__ pros, const float* __restrict__ wout,
    const float* __restrict__ bout, float* __restrict__ out) {
  __shared__ float wlds[32 * 260];
  const int tid = threadIdx.x;
  const int m0  = blockIdx.x * 256;
#pragma unroll
  for (int i = 0; i < 8; ++i) {
    int f4  = tid + i * 256;   // 0..2047 float4s of w_out
    int col = f4 >> 6;
    int k4  = (f4 & 63) * 4;
    *(float4*)&wlds[col * 260 + k4] = *(const float4*)(wout + (size_t)col * 256 + k4);
  }
  __syncthreads();
  const int rb = tid >> 3;  // 0..31
  const int cg = tid & 7;   // 0..7
  float acc[8][4];
#pragma unroll
  for (int a = 0; a < 8; ++a)
#pragma unroll
    for (int b = 0; b < 4; ++b) acc[a][b] = 0.f;

  for (int kk = 0; kk < 256; kk += 4) {
    float4 wv[4];
#pragma unroll
    for (int cc = 0; cc < 4; ++cc)
      wv[cc] = *(const float4*)&wlds[(cg + 8 * cc) * 260 + kk];
#pragma unroll
    for (int ri = 0; ri < 8; ++ri) {
      f16x4 xv = *(const f16x4*)(pros + (size_t)(m0 + rb + 32 * ri) * 256 + kk);
      float x0 = (float)xv[0], x1 = (float)xv[1];
      float x2 = (float)xv[2], x3 = (float)xv[3];
#pragma unroll
      for (int cc = 0; cc < 4; ++cc)
        acc[ri][cc] += x0 * wv[cc].x + x1 * wv[cc].y + x2 * wv[cc].z + x3 * wv[cc].w;
    }
  }
#pragma unroll
  for (int cc = 0; cc < 4; ++cc) {
    float bias = bout[cg + 8 * cc];
#pragma unroll
    for (int ri = 0; ri < 8; ++ri)
      out[(size_t)(m0 + rb + 32 * ri) * BOT + cg + 8 * cc] = acc[ri][cc] + bias;
  }
}

extern "C" void kernel_launch(void* const* d_in, const int* in_sizes, int n_in,
                              void* d_out, int out_size, void* d_ws, size_t ws_size,
                              hipStream_t stream) {
  const float* x      = (const float*)d_in[0];
  const float* w_ih_f = (const float*)d_in[1];
  const float* w_hh_f = (const float*)d_in[2];
  const float* b_ih_f = (const float*)d_in[3];
  const float* b_hh_f = (const float*)d_in[4];
  const float* w_ih_b = (const float*)d_in[5];
  const float* w_hh_b = (const float*)d_in[6];
  const float* b_ih_b = (const float*)d_in[7];
  const float* b_hh_b = (const float*)d_in[8];
  const float* w_out  = (const float*)d_in[9];
  const float* b_out  = (const float*)d_in[10];
  float* out = (float*)d_out;

  // ws layout: gx f16 [65536][768] = 96 MiB, pros f16 [65536][256] = 32 MiB
  _Float16* gx   = (_Float16*)d_ws;
  _Float16* pros = (_Float16*)((char*)d_ws + (size_t)MM * GXC * sizeof(_Float16));

  gx_gemm<<<dim3(512, 6), 256, 0, stream>>>(x, w_ih_f, w_ih_b, gx);
  gru_scan<<<128, 256, 0, stream>>>(gx, w_hh_f, w_hh_b, b_ih_f, b_hh_f,
                                    b_ih_b, b_hh_b, pros);
  out_proj<<<256, 256, 0, stream>>>(pros, w_out, b_out, out);
}

// Round 2
// 828.219 us; speedup vs baseline: 1.1678x; 1.1678x over previous
//
#include <hip/hip_runtime.h>

#define NB 64
#define TSTEPS 1024
#define EE 256
#define HH 128
#define MM (NB * TSTEPS)   // 65536 rows
#define GXC 768            // 384 fwd gates + 384 bwd gates
#define BOT 32
#define CH 16              // scan gx-staging chunk (steps)

typedef float    f32x4 __attribute__((ext_vector_type(4)));
typedef _Float16 f16x2 __attribute__((ext_vector_type(2)));
typedef _Float16 f16x4 __attribute__((ext_vector_type(4)));
typedef _Float16 f16x8 __attribute__((ext_vector_type(8)));

#if defined(__has_builtin)
#if __has_builtin(__builtin_amdgcn_fdot2)
#define HAVE_FDOT2 1
#endif
#endif

__device__ __forceinline__ float fdot2f(f16x2 a, f16x2 b, float c) {
#ifdef HAVE_FDOT2
  return __builtin_amdgcn_fdot2(a, b, c, false);
#else
  return c + (float)a[0] * (float)b[0] + (float)a[1] * (float)b[1];
#endif
}

__device__ __forceinline__ f16x2 mkh2(float a, float b) {
  f16x2 r; r[0] = (_Float16)a; r[1] = (_Float16)b; return r;
}

// ---------------------------------------------------------------------------
// Kernel A: gx[m][g] = sum_e x[m][e] * w_ih[g][e]   (f16 MFMA, f32 accum)
// Unchanged from R1.
// ---------------------------------------------------------------------------
__global__ __launch_bounds__(256) void gx_gemm(
    const float* __restrict__ x, const float* __restrict__ wf,
    const float* __restrict__ wb, _Float16* __restrict__ gx) {
  __shared__ _Float16 As[128 * 72];
  __shared__ _Float16 Bs[128 * 72];
  const int tid = threadIdx.x;
  const int m0  = blockIdx.x * 128;
  const int by  = blockIdx.y;  // 0..5 (3 col-blocks per direction)
  const float* wsrc = (by < 3) ? (wf + (size_t)(by * 128) * 256)
                               : (wb + (size_t)((by - 3) * 128) * 256);
  const int g0 = by * 128;

  const int lane = tid & 63;
  const int wid  = tid >> 6;
  const int wr = wid & 1, wc = wid >> 1;  // 2x2 wave grid, 64x64 per wave
  const int fm = lane & 15;               // fragment m/n index
  const int fk = (lane >> 4) * 8;         // fragment k offset (8 contiguous)

  f32x4 acc[4][4];
#pragma unroll
  for (int a = 0; a < 4; ++a)
#pragma unroll
    for (int b = 0; b < 4; ++b) acc[a][b] = (f32x4)0.0f;

  for (int kc = 0; kc < 4; ++kc) {
    const int k0 = kc * 64;
    if (kc) __syncthreads();
#pragma unroll
    for (int i = 0; i < 8; ++i) {
      int idx = tid + i * 256;          // float4 index within 128x64 chunk
      int row = idx >> 4;
      int k4  = (idx & 15) * 4;
      float4 av = *(const float4*)(x + (size_t)(m0 + row) * 256 + k0 + k4);
      float4 bv = *(const float4*)(wsrc + (size_t)row * 256 + k0 + k4);
      f16x4 ah, bh;
      ah[0] = (_Float16)av.x; ah[1] = (_Float16)av.y;
      ah[2] = (_Float16)av.z; ah[3] = (_Float16)av.w;
      bh[0] = (_Float16)bv.x; bh[1] = (_Float16)bv.y;
      bh[2] = (_Float16)bv.z; bh[3] = (_Float16)bv.w;
      *(f16x4*)&As[row * 72 + k4] = ah;
      *(f16x4*)&Bs[row * 72 + k4] = bh;
    }
    __syncthreads();
#pragma unroll
    for (int ks = 0; ks < 2; ++ks) {
      f16x8 af[4], bf[4];
#pragma unroll
      for (int tmn = 0; tmn < 4; ++tmn) {
        af[tmn] = *(const f16x8*)&As[(wr * 64 + tmn * 16 + fm) * 72 + ks * 32 + fk];
        bf[tmn] = *(const f16x8*)&Bs[(wc * 64 + tmn * 16 + fm) * 72 + ks * 32 + fk];
      }
#pragma unroll
      for (int tm = 0; tm < 4; ++tm)
#pragma unroll
        for (int tn = 0; tn < 4; ++tn)
          acc[tm][tn] = __builtin_amdgcn_mfma_f32_16x16x32_f16(
              af[tm], bf[tn], acc[tm][tn], 0, 0, 0);
    }
  }

  // epilogue: C/D layout col = lane&15, row = (lane>>4)*4 + reg  [m89/m91]
  const int rq = (lane >> 4) * 4;
#pragma unroll
  for (int tm = 0; tm < 4; ++tm)
#pragma unroll
    for (int tn = 0; tn < 4; ++tn)
#pragma unroll
      for (int v = 0; v < 4; ++v) {
        int m = m0 + wr * 64 + tm * 16 + rq + v;
        int g = g0 + wc * 64 + tn * 16 + fm;
        gx[(size_t)m * GXC + g] = (_Float16)acc[tm][tn][v];
      }
}

// ---------------------------------------------------------------------------
// Kernel B: GRU scan. 128 blocks = 64 batch x 2 dirs, 256 thr = 128 h x 2 K-halves.
// R2 change: gx staged through LDS in 16-step double-buffered chunks.
// Global loads for chunk c+1 issue at chunk-c top into REGISTERS (no barrier
// drain), ds_write lands mid-chunk (s==7) when vmcnt is long since retired.
// Per-step gx access = 3x ds_read_u16 issued under the dot phase.
// ---------------------------------------------------------------------------
__global__ __launch_bounds__(256) void gru_scan(
    const _Float16* __restrict__ gx,
    const float* __restrict__ whf, const float* __restrict__ whb,
    const float* __restrict__ bihf, const float* __restrict__ bhhf,
    const float* __restrict__ bihb, const float* __restrict__ bhhb,
    _Float16* __restrict__ pros) {
  const int bid = blockIdx.x;
  const int dir = bid & 1;
  const int n   = bid >> 1;
  const float* whh = dir ? whb : whf;
  const float* bih = dir ? bihb : bihf;
  const float* bhh = dir ? bhhb : bhhf;

  const int tid = threadIdx.x;
  const int j = tid & 127;   // h index
  const int c = tid >> 7;    // K-half (wave-uniform)

  __shared__ __align__(16) _Float16 hsh[128];
  __shared__ float pr[128], pz[128], pn[128];
  __shared__ __align__(16) _Float16 gbuf[2][CH * 384];  // 24 KB staging

  // preload w_hh rows j (r), 128+j (z), 256+j (n), k in [c*64, c*64+64)
  f16x2 wrk[32], wzk[32], wnk[32];
  {
    const int kb = c * 64;
#pragma unroll
    for (int i = 0; i < 32; ++i) {
      int k = kb + 2 * i;
      float2 a = *(const float2*)(whh + (size_t)j * HH + k);
      float2 b = *(const float2*)(whh + (size_t)(HH + j) * HH + k);
      float2 d = *(const float2*)(whh + (size_t)(2 * HH + j) * HH + k);
      wrk[i] = mkh2(a.x, a.y);
      wzk[i] = mkh2(b.x, b.y);
      wnk[i] = mkh2(d.x, d.y);
    }
  }
  float br = 0.f, bz = 0.f, bni = 0.f, bnh = 0.f;
  if (!c) {
    br  = bih[j] + bhh[j];
    bz  = bih[HH + j] + bhh[HH + j];
    bni = bih[2 * HH + j];
    bnh = bhh[2 * HH + j];
  }
  if (tid < 128) hsh[tid] = (_Float16)0.f;

  // per-thread staging units: u = tid, tid+256, tid+512 over 768 f16x8 units
  // (48 units per step row of 384 halves)
  f16x8 stage[3];
  int su[3], sc8[3];
#pragma unroll
  for (int i = 0; i < 3; ++i) {
    int u = tid + i * 256;
    su[i]  = u / 48;             // step-in-chunk
    sc8[i] = (u - su[i] * 48) * 8;  // half-offset within the 384-col row
  }
  auto load_chunk = [&](int ch) {
#pragma unroll
    for (int i = 0; i < 3; ++i) {
      int t  = ch * CH + su[i];
      int tt = dir ? (TSTEPS - 1 - t) : t;
      stage[i] = *(const f16x8*)(gx + ((size_t)(n * TSTEPS + tt)) * GXC +
                                 dir * 384 + sc8[i]);
    }
  };
  auto write_chunk = [&](int buf) {
#pragma unroll
    for (int i = 0; i < 3; ++i)
      *(f16x8*)&gbuf[buf][su[i] * 384 + sc8[i]] = stage[i];
  };

  load_chunk(0);
  write_chunk(0);
  __syncthreads();

  const int NCH = TSTEPS / CH;
#pragma unroll 1
  for (int ch = 0; ch < NCH; ++ch) {
    const int buf = ch & 1;
    if (ch + 1 < NCH) load_chunk(ch + 1);  // regs; vmcnt retires by s==7
#pragma unroll 1
    for (int s = 0; s < CH; ++s) {
      const int t  = ch * CH + s;
      const int tt = dir ? (TSTEPS - 1 - t) : t;
      // gx reads issued early so lgkm latency hides under the dot phase
      float gxr = 0.f, gxz = 0.f, gxn = 0.f;
      if (!c) {
        const _Float16* gr = &gbuf[buf][s * 384];
        gxr = (float)gr[j];
        gxz = (float)gr[HH + j];
        gxn = (float)gr[2 * HH + j];
      }
      float ar = 0.f, az = 0.f, an = 0.f;
      const f16x8* hp = (const f16x8*)&hsh[c * 64];
#pragma unroll
      for (int i = 0; i < 8; ++i) {
        f16x8 hv = hp[i];
#pragma unroll
        for (int q = 0; q < 4; ++q) {
          f16x2 hh; hh[0] = hv[2 * q]; hh[1] = hv[2 * q + 1];
          int idx = i * 4 + q;
          ar = fdot2f(wrk[idx], hh, ar);
          az = fdot2f(wzk[idx], hh, az);
          an = fdot2f(wnk[idx], hh, an);
        }
      }
      if (c) { pr[j] = ar; pz[j] = az; pn[j] = an; }
      if (s == 7 && ch + 1 < NCH) write_chunk(buf ^ 1);  // vmcnt free by now
      __syncthreads();
      if (!c) {
        float ghr = ar + pr[j], ghz = az + pz[j], ghn = an + pn[j];
        float rv = 1.f / (1.f + __expf(-(gxr + br + ghr)));
        float zv = 1.f / (1.f + __expf(-(gxz + bz + ghz)));
        float na = gxn + bni + rv * (ghn + bnh);
        na = fminf(15.f, fmaxf(-15.f, na));
        float e  = __expf(-2.f * na);
        float nn = (1.f - e) / (1.f + e);
        float hold = (float)hsh[j];
        float hnew = nn + zv * (hold - nn);    // (1-z)*n + z*h
        hsh[j] = (_Float16)hnew;
        pros[((size_t)(n * TSTEPS + tt)) * EE + dir * HH + j] = (_Float16)hnew;
      }
      __syncthreads();
    }
  }
}

// ---------------------------------------------------------------------------
// Kernel C: out[m][o] = pros[m][:] . w_out[o][:] + b_out[o]
// Unchanged from R1.
// ---------------------------------------------------------------------------
__global__ __launch_bounds__(256) void out_proj(
    const _Float16* __restrict__ pros, const float* __restrict__ wout,
    const float* __restrict__ bout, float* __restrict__ out) {
  __shared__ float wlds[32 * 260];
  const int tid = threadIdx.x;
  const int m0  = blockIdx.x * 256;
#pragma unroll
  for (int i = 0; i < 8; ++i) {
    int f4  = tid + i * 256;   // 0..2047 float4s of w_out
    int col = f4 >> 6;
    int k4  = (f4 & 63) * 4;
    *(float4*)&wlds[col * 260 + k4] = *(const float4*)(wout + (size_t)col * 256 + k4);
  }
  __syncthreads();
  const int rb = tid >> 3;  // 0..31
  const int cg = tid & 7;   // 0..7
  float acc[8][4];
#pragma unroll
  for (int a = 0; a < 8; ++a)
#pragma unroll
    for (int b = 0; b < 4; ++b) acc[a][b] = 0.f;

  for (int kk = 0; kk < 256; kk += 4) {
    float4 wv[4];
#pragma unroll
    for (int cc = 0; cc < 4; ++cc)
      wv[cc] = *(const float4*)&wlds[(cg + 8 * cc) * 260 + kk];
#pragma unroll
    for (int ri = 0; ri < 8; ++ri) {
      f16x4 xv = *(const f16x4*)(pros + (size_t)(m0 + rb + 32 * ri) * 256 + kk);
      float x0 = (float)xv[0], x1 = (float)xv[1];
      float x2 = (float)xv[2], x3 = (float)xv[3];
#pragma unroll
      for (int cc = 0; cc < 4; ++cc)
        acc[ri][cc] += x0 * wv[cc].x + x1 * wv[cc].y + x2 * wv[cc].z + x3 * wv[cc].w;
    }
  }
#pragma unroll
  for (int cc = 0; cc < 4; ++cc) {
    float bias = bout[cg + 8 * cc];
#pragma unroll
    for (int ri = 0; ri < 8; ++ri)
      out[(size_t)(m0 + rb + 32 * ri) * BOT + cg + 8 * cc] = acc[ri][cc] + bias;
  }
}

extern "C" void kernel_launch(void* const* d_in, const int* in_sizes, int n_in,
                              void* d_out, int out_size, void* d_ws, size_t ws_size,
                              hipStream_t stream) {
  const float* x      = (const float*)d_in[0];
  const float* w_ih_f = (const float*)d_in[1];
  const float* w_hh_f = (const float*)d_in[2];
  const float* b_ih_f = (const float*)d_in[3];
  const float* b_hh_f = (const float*)d_in[4];
  const float* w_ih_b = (const float*)d_in[5];
  const float* w_hh_b = (const float*)d_in[6];
  const float* b_ih_b = (const float*)d_in[7];
  const float* b_hh_b = (const float*)d_in[8];
  const float* w_out  = (const float*)d_in[9];
  const float* b_out  = (const float*)d_in[10];
  float* out = (float*)d_out;

  // ws layout: gx f16 [65536][768] = 96 MiB, pros f16 [65536][256] = 32 MiB
  _Float16* gx   = (_Float16*)d_ws;
  _Float16* pros = (_Float16*)((char*)d_ws + (size_t)MM * GXC * sizeof(_Float16));

  gx_gemm<<<dim3(512, 6), 256, 0, stream>>>(x, w_ih_f, w_ih_b, gx);
  gru_scan<<<128, 256, 0, stream>>>(gx, w_hh_f, w_hh_b, b_ih_f, b_hh_f,
                                    b_ih_b, b_hh_b, pros);
  out_proj<<<256, 256, 0, stream>>>(pros, w_out, b_out, out);
}

// Round 3
// 731.189 us; speedup vs baseline: 1.3228x; 1.1327x over previous
//
#include <hip/hip_runtime.h>

#define NB 64
#define TSTEPS 1024
#define EE 256
#define HH 128
#define MM (NB * TSTEPS)   // 65536 rows
#define GXC 768            // 384 fwd gates + 384 bwd gates
#define BOT 32
#define CH 16              // scan gx-staging chunk (steps)

typedef float    f32x4 __attribute__((ext_vector_type(4)));
typedef _Float16 f16x2 __attribute__((ext_vector_type(2)));
typedef _Float16 f16x4 __attribute__((ext_vector_type(4)));
typedef _Float16 f16x8 __attribute__((ext_vector_type(8)));

#if defined(__has_builtin)
#if __has_builtin(__builtin_amdgcn_fdot2)
#define HAVE_FDOT2 1
#endif
#if __has_builtin(__builtin_amdgcn_rcpf)
#define HAVE_RCPF 1
#endif
#endif

__device__ __forceinline__ float fdot2f(f16x2 a, f16x2 b, float c) {
#ifdef HAVE_FDOT2
  return __builtin_amdgcn_fdot2(a, b, c, false);
#else
  return c + (float)a[0] * (float)b[0] + (float)a[1] * (float)b[1];
#endif
}

__device__ __forceinline__ float rcpf(float x) {
#ifdef HAVE_RCPF
  return __builtin_amdgcn_rcpf(x);
#else
  return 1.0f / x;
#endif
}

__device__ __forceinline__ f16x2 mkh2(float a, float b) {
  f16x2 r; r[0] = (_Float16)a; r[1] = (_Float16)b; return r;
}

// ---------------------------------------------------------------------------
// Kernel A: gx[m][g] = sum_e x[m][e] * w_ih[g][e]   (f16 MFMA, f32 accum)
// Unchanged from R2.
// ---------------------------------------------------------------------------
__global__ __launch_bounds__(256) void gx_gemm(
    const float* __restrict__ x, const float* __restrict__ wf,
    const float* __restrict__ wb, _Float16* __restrict__ gx) {
  __shared__ _Float16 As[128 * 72];
  __shared__ _Float16 Bs[128 * 72];
  const int tid = threadIdx.x;
  const int m0  = blockIdx.x * 128;
  const int by  = blockIdx.y;  // 0..5 (3 col-blocks per direction)
  const float* wsrc = (by < 3) ? (wf + (size_t)(by * 128) * 256)
                               : (wb + (size_t)((by - 3) * 128) * 256);
  const int g0 = by * 128;

  const int lane = tid & 63;
  const int wid  = tid >> 6;
  const int wr = wid & 1, wc = wid >> 1;  // 2x2 wave grid, 64x64 per wave
  const int fm = lane & 15;               // fragment m/n index
  const int fk = (lane >> 4) * 8;         // fragment k offset (8 contiguous)

  f32x4 acc[4][4];
#pragma unroll
  for (int a = 0; a < 4; ++a)
#pragma unroll
    for (int b = 0; b < 4; ++b) acc[a][b] = (f32x4)0.0f;

  for (int kc = 0; kc < 4; ++kc) {
    const int k0 = kc * 64;
    if (kc) __syncthreads();
#pragma unroll
    for (int i = 0; i < 8; ++i) {
      int idx = tid + i * 256;          // float4 index within 128x64 chunk
      int row = idx >> 4;
      int k4  = (idx & 15) * 4;
      float4 av = *(const float4*)(x + (size_t)(m0 + row) * 256 + k0 + k4);
      float4 bv = *(const float4*)(wsrc + (size_t)row * 256 + k0 + k4);
      f16x4 ah, bh;
      ah[0] = (_Float16)av.x; ah[1] = (_Float16)av.y;
      ah[2] = (_Float16)av.z; ah[3] = (_Float16)av.w;
      bh[0] = (_Float16)bv.x; bh[1] = (_Float16)bv.y;
      bh[2] = (_Float16)bv.z; bh[3] = (_Float16)bv.w;
      *(f16x4*)&As[row * 72 + k4] = ah;
      *(f16x4*)&Bs[row * 72 + k4] = bh;
    }
    __syncthreads();
#pragma unroll
    for (int ks = 0; ks < 2; ++ks) {
      f16x8 af[4], bf[4];
#pragma unroll
      for (int tmn = 0; tmn < 4; ++tmn) {
        af[tmn] = *(const f16x8*)&As[(wr * 64 + tmn * 16 + fm) * 72 + ks * 32 + fk];
        bf[tmn] = *(const f16x8*)&Bs[(wc * 64 + tmn * 16 + fm) * 72 + ks * 32 + fk];
      }
#pragma unroll
      for (int tm = 0; tm < 4; ++tm)
#pragma unroll
        for (int tn = 0; tn < 4; ++tn)
          acc[tm][tn] = __builtin_amdgcn_mfma_f32_16x16x32_f16(
              af[tm], bf[tn], acc[tm][tn], 0, 0, 0);
    }
  }

  // epilogue: C/D layout col = lane&15, row = (lane>>4)*4 + reg  [m89/m91]
  const int rq = (lane >> 4) * 4;
#pragma unroll
  for (int tm = 0; tm < 4; ++tm)
#pragma unroll
    for (int tn = 0; tn < 4; ++tn)
#pragma unroll
      for (int v = 0; v < 4; ++v) {
        int m = m0 + wr * 64 + tm * 16 + rq + v;
        int g = g0 + wc * 64 + tn * 16 + fm;
        gx[(size_t)m * GXC + g] = (_Float16)acc[tm][tn][v];
      }
}

// ---------------------------------------------------------------------------
// Kernel B: GRU scan. 128 blocks = 64 batch x 2 dirs, 256 thr.
// R3: lane = jj(32 per wave) x K-half(c = lane>>5). Partial K-sums combine
// via __shfl_xor(32) — no LDS round-trip, no second barrier. h double-
// buffered in LDS so ONE barrier/step suffices; h_prev kept in a register
// (tail computed redundantly in both c-lanes). Sigmoid/tanh use v_rcp_f32.
// gx staged through LDS in 16-step double-buffered chunks (from R2).
// ---------------------------------------------------------------------------
__global__ __launch_bounds__(256) void gru_scan(
    const _Float16* __restrict__ gx,
    const float* __restrict__ whf, const float* __restrict__ whb,
    const float* __restrict__ bihf, const float* __restrict__ bhhf,
    const float* __restrict__ bihb, const float* __restrict__ bhhb,
    _Float16* __restrict__ pros) {
  const int bid = blockIdx.x;
  const int dir = bid & 1;
  const int n   = bid >> 1;
  const float* whh = dir ? whb : whf;
  const float* bih = dir ? bihb : bihf;
  const float* bhh = dir ? bhhb : bhhf;

  const int tid  = threadIdx.x;
  const int lane = tid & 63;
  const int jj   = ((tid >> 6) << 5) | (lane & 31);  // h index 0..127
  const int c    = lane >> 5;                        // K-half (in-wave!)

  __shared__ __align__(16) _Float16 hbuf[2][128];
  __shared__ __align__(16) _Float16 gbuf[2][CH * 384];  // 24 KB staging

  // preload w_hh rows jj (r), 128+jj (z), 256+jj (n), k in [c*64, c*64+64)
  f16x2 wrk[32], wzk[32], wnk[32];
  {
    const int kb = c * 64;
#pragma unroll
    for (int i = 0; i < 32; ++i) {
      int k = kb + 2 * i;
      float2 a = *(const float2*)(whh + (size_t)jj * HH + k);
      float2 b = *(const float2*)(whh + (size_t)(HH + jj) * HH + k);
      float2 d = *(const float2*)(whh + (size_t)(2 * HH + jj) * HH + k);
      wrk[i] = mkh2(a.x, a.y);
      wzk[i] = mkh2(b.x, b.y);
      wnk[i] = mkh2(d.x, d.y);
    }
  }
  // biases (all lanes, redundant across c)
  const float br  = bih[jj] + bhh[jj];
  const float bz  = bih[HH + jj] + bhh[HH + jj];
  const float bni = bih[2 * HH + jj];
  const float bnh = bhh[2 * HH + jj];

  if (tid < 128) hbuf[0][tid] = (_Float16)0.f;
  float hprev = 0.f;

  // per-thread staging units: u = tid, tid+256, tid+512 over 768 f16x8 units
  f16x8 stage[3];
  int su[3], sc8[3];
#pragma unroll
  for (int i = 0; i < 3; ++i) {
    int u = tid + i * 256;
    su[i]  = u / 48;                 // step-in-chunk
    sc8[i] = (u - su[i] * 48) * 8;   // half-offset within the 384-col row
  }
  auto load_chunk = [&](int ch) {
#pragma unroll
    for (int i = 0; i < 3; ++i) {
      int t  = ch * CH + su[i];
      int tt = dir ? (TSTEPS - 1 - t) : t;
      stage[i] = *(const f16x8*)(gx + ((size_t)(n * TSTEPS + tt)) * GXC +
                                 dir * 384 + sc8[i]);
    }
  };
  auto write_chunk = [&](int buf) {
#pragma unroll
    for (int i = 0; i < 3; ++i)
      *(f16x8*)&gbuf[buf][su[i] * 384 + sc8[i]] = stage[i];
  };

  load_chunk(0);
  write_chunk(0);
  __syncthreads();

  int p = 0;
  const int NCH = TSTEPS / CH;
#pragma unroll 1
  for (int ch = 0; ch < NCH; ++ch) {
    const int buf = ch & 1;
    if (ch + 1 < NCH) load_chunk(ch + 1);  // into regs; retires mid-chunk
#pragma unroll 1
    for (int s = 0; s < CH; ++s) {
      const int t  = ch * CH + s;
      const int tt = dir ? (TSTEPS - 1 - t) : t;
      // gx reads (LDS broadcast) — issued early, consumed in tail
      const _Float16* gr = &gbuf[buf][s * 384];
      const float gxr = (float)gr[jj];
      const float gxz = (float)gr[HH + jj];
      const float gxn = (float)gr[2 * HH + jj];
      // dot phase: 96 v_dot2 over this lane's K-half
      float ar = 0.f, az = 0.f, an = 0.f;
      const f16x8* hp = (const f16x8*)&hbuf[p][c * 64];
#pragma unroll
      for (int i = 0; i < 8; ++i) {
        f16x8 hv = hp[i];
#pragma unroll
        for (int q = 0; q < 4; ++q) {
          f16x2 hh; hh[0] = hv[2 * q]; hh[1] = hv[2 * q + 1];
          int idx = i * 4 + q;
          ar = fdot2f(wrk[idx], hh, ar);
          az = fdot2f(wzk[idx], hh, az);
          an = fdot2f(wnk[idx], hh, an);
        }
      }
      // combine K-halves in-wave (no barrier, no LDS)
      ar += __shfl_xor(ar, 32);
      az += __shfl_xor(az, 32);
      an += __shfl_xor(an, 32);
      // tail (computed redundantly in both c-lanes, fast rcp)
      const float rv = rcpf(1.f + __expf(-(gxr + br + ar)));
      const float zv = rcpf(1.f + __expf(-(gxz + bz + az)));
      float na = gxn + bni + rv * (an + bnh);
      na = fminf(15.f, fmaxf(-15.f, na));
      const float e  = __expf(-2.f * na);
      const float nn = (1.f - e) * rcpf(1.f + e);
      const float hnew = nn + zv * (hprev - nn);   // (1-z)*n + z*h
      hprev = hnew;
      if (c == 0) {
        hbuf[p ^ 1][jj] = (_Float16)hnew;
        pros[((size_t)(n * TSTEPS + tt)) * EE + dir * HH + jj] = (_Float16)hnew;
      }
      if (s == 7 && ch + 1 < NCH) write_chunk(buf ^ 1);  // vmcnt free by now
      __syncthreads();
      p ^= 1;
    }
  }
}

// ---------------------------------------------------------------------------
// Kernel C: out[m][o] = pros[m][:] . w_out[o][:] + b_out[o]
// Unchanged from R2.
// ---------------------------------------------------------------------------
__global__ __launch_bounds__(256) void out_proj(
    const _Float16* __restrict__ pros, const float* __restrict__ wout,
    const float* __restrict__ bout, float* __restrict__ out) {
  __shared__ float wlds[32 * 260];
  const int tid = threadIdx.x;
  const int m0  = blockIdx.x * 256;
#pragma unroll
  for (int i = 0; i < 8; ++i) {
    int f4  = tid + i * 256;   // 0..2047 float4s of w_out
    int col = f4 >> 6;
    int k4  = (f4 & 63) * 4;
    *(float4*)&wlds[col * 260 + k4] = *(const float4*)(wout + (size_t)col * 256 + k4);
  }
  __syncthreads();
  const int rb = tid >> 3;  // 0..31
  const int cg = tid & 7;   // 0..7
  float acc[8][4];
#pragma unroll
  for (int a = 0; a < 8; ++a)
#pragma unroll
    for (int b = 0; b < 4; ++b) acc[a][b] = 0.f;

  for (int kk = 0; kk < 256; kk += 4) {
    float4 wv[4];
#pragma unroll
    for (int cc = 0; cc < 4; ++cc)
      wv[cc] = *(const float4*)&wlds[(cg + 8 * cc) * 260 + kk];
#pragma unroll
    for (int ri = 0; ri < 8; ++ri) {
      f16x4 xv = *(const f16x4*)(pros + (size_t)(m0 + rb + 32 * ri) * 256 + kk);
      float x0 = (float)xv[0], x1 = (float)xv[1];
      float x2 = (float)xv[2], x3 = (float)xv[3];
#pragma unroll
      for (int cc = 0; cc < 4; ++cc)
        acc[ri][cc] += x0 * wv[cc].x + x1 * wv[cc].y + x2 * wv[cc].z + x3 * wv[cc].w;
    }
  }
#pragma unroll
  for (int cc = 0; cc < 4; ++cc) {
    float bias = bout[cg + 8 * cc];
#pragma unroll
    for (int ri = 0; ri < 8; ++ri)
      out[(size_t)(m0 + rb + 32 * ri) * BOT + cg + 8 * cc] = acc[ri][cc] + bias;
  }
}

extern "C" void kernel_launch(void* const* d_in, const int* in_sizes, int n_in,
                              void* d_out, int out_size, void* d_ws, size_t ws_size,
                              hipStream_t stream) {
  const float* x      = (const float*)d_in[0];
  const float* w_ih_f = (const float*)d_in[1];
  const float* w_hh_f = (const float*)d_in[2];
  const float* b_ih_f = (const float*)d_in[3];
  const float* b_hh_f = (const float*)d_in[4];
  const float* w_ih_b = (const float*)d_in[5];
  const float* w_hh_b = (const float*)d_in[6];
  const float* b_ih_b = (const float*)d_in[7];
  const float* b_hh_b = (const float*)d_in[8];
  const float* w_out  = (const float*)d_in[9];
  const float* b_out  = (const float*)d_in[10];
  float* out = (float*)d_out;

  // ws layout: gx f16 [65536][768] = 96 MiB, pros f16 [65536][256] = 32 MiB
  _Float16* gx   = (_Float16*)d_ws;
  _Float16* pros = (_Float16*)((char*)d_ws + (size_t)MM * GXC * sizeof(_Float16));

  gx_gemm<<<dim3(512, 6), 256, 0, stream>>>(x, w_ih_f, w_ih_b, gx);
  gru_scan<<<128, 256, 0, stream>>>(gx, w_hh_f, w_hh_b, b_ih_f, b_hh_f,
                                    b_ih_b, b_hh_b, pros);
  out_proj<<<256, 256, 0, stream>>>(pros, w_out, b_out, out);
}